// Round 1
// baseline (405.108 us; speedup 1.0000x reference)
//
#include <hip/hip_runtime.h>
#include <hip/hip_bf16.h>
#include <stdint.h>

#define D      256
#define K      8192
#define NROWS  32768          // 16 * 2048
#define QELEMS 8388608        // NROWS * D
// d_out layout (flat f32): [0,QELEMS) quantized, [QELEMS,QELEMS+NROWS) idx, [QELEMS+NROWS] loss

typedef __attribute__((ext_vector_type(8))) short bf16x8;
typedef __attribute__((ext_vector_type(4))) float f32x4;
typedef unsigned int u32;
typedef unsigned short u16;

__device__ __forceinline__ u16 f2bf(float f) {
    u32 b = __float_as_uint(f);
    return (u16)((b + 0x7fffu + ((b >> 16) & 1u)) >> 16);   // RNE
}

// ---------------------------------------------------------------------------
// Prep: cb fp32 -> ch bf16, se[k] = ||cb[k]||^2, zero loss accumulator.
__global__ __launch_bounds__(256) void vq_prep_kernel(
    const float* __restrict__ cb, u16* __restrict__ ch,
    float* __restrict__ se, float* __restrict__ loss_sum) {
    int row = blockIdx.x * 4 + (threadIdx.x >> 6);
    int l = threadIdx.x & 63;
    float4 v = *(const float4*)(cb + (size_t)row * D + l * 4);
    ushort4 o;
    o.x = f2bf(v.x); o.y = f2bf(v.y); o.z = f2bf(v.z); o.w = f2bf(v.w);
    *(ushort4*)(ch + (size_t)row * D + l * 4) = o;
    float s = v.x * v.x + v.y * v.y + v.z * v.z + v.w * v.w;
    #pragma unroll
    for (int off = 32; off > 0; off >>= 1) s += __shfl_down(s, off, 64);
    if (l == 0) se[row] = s;
    if (blockIdx.x == 0 && threadIdx.x == 0) *loss_sum = 0.f;
}

// ---------------------------------------------------------------------------
// Filter: bf16 MFMA scan. NEW partition: every wave owns ONE 16-code m-slice
// of the 64-code tile and ALL 64 rows of the block (Bf[4][8] = 128 VGPR).
// Per c-iter: 1 ds_read_b128 feeds 4 MFMA (A-frag reuse 4x, was 2x) -> LDS
// pipe demand halved (768 -> 384 cyc/CU per tile). A-tile (64 codes x 256 d,
// 32 KB) double-buffered via async global_load_lds, ONE barrier per tile.
// Block = 256 thr, 64 rows/block, grid 512, 2 blocks/CU (launch_bounds(256,2)).
// Per-row candidates: 16 (wave,l4) groups x top-2 = 32, merged at kernel end
// in LDS to 8 slots x best-2-of-union = 16 (same robustness as old 8-slot
// top-2; rescore unchanged).
__global__ __launch_bounds__(256, 2) void vq_filter_kernel(
    const u16* __restrict__ ch, const float* __restrict__ x,
    const float* __restrict__ se, u32* __restrict__ cand)
{
    __shared__ __align__(16) u16 As[2][16384];   // 2 x 32 KB: 64 codes x 256 d, frag order

    const int tid  = threadIdx.x;
    const int lane = tid & 63;
    const int wave = tid >> 6;         // 0..3 : which 16-code slice of the tile
    const int l15  = lane & 15;
    const int l4   = lane >> 4;        // 0..3
    const int row0 = blockIdx.x * 64;

    // ---- B operand: ALL 64 block rows x 256 d in registers, f2bf in-register
    bf16x8 Bf[4][8];                   // 128 VGPRs
    #pragma unroll
    for (int nt = 0; nt < 4; ++nt) {
        const float* xr = x + (size_t)(row0 + nt * 16 + l15) * D + l4 * 8;
        #pragma unroll
        for (int c = 0; c < 8; ++c) {
            float4 a = *(const float4*)(xr + c * 32);
            float4 b = *(const float4*)(xr + c * 32 + 4);
            bf16x8 f;
            f[0] = (short)f2bf(a.x); f[1] = (short)f2bf(a.y);
            f[2] = (short)f2bf(a.z); f[3] = (short)f2bf(a.w);
            f[4] = (short)f2bf(b.x); f[5] = (short)f2bf(b.y);
            f[6] = (short)f2bf(b.z); f[7] = (short)f2bf(b.w);
            Bf[nt][c] = f;
        }
    }

    // per-lane top-2 (value, code) per nt-row
    float b0[4], b1[4]; int c0[4], c1[4];
    #pragma unroll
    for (int nt = 0; nt < 4; ++nt) { b0[nt] = 1e30f; b1[nt] = 1e30f; c0[nt] = 0; c1[nt] = 0; }

    // ---- prologue: stage tile 0 into buffer 0 (8 async instrs/wave) ----
    // chunk g in [0,32): code-group mg=g&3 (16 codes), d-chunk c=g>>2 (32 d).
    #pragma unroll
    for (int i = 0; i < 8; ++i) {
        int g = wave * 8 + i;
        const u16* gp = ch + (size_t)((g & 3) * 16 + l15) * D + (g >> 2) * 32 + l4 * 8;
        u16* lb = &As[0][(size_t)g * 512];          // wave-uniform; HW adds lane*16B
        __builtin_amdgcn_global_load_lds(
            (const __attribute__((address_space(1))) u32*)gp,
            (__attribute__((address_space(3))) u32*)lb, 16, 0, 0);
    }
    __syncthreads();

    int buf = 0;
    #pragma unroll 1
    for (int ct = 0; ct < 128; ++ct) {
        const int k0 = ct << 6;

        // prefetch tile ct+1 into As[buf^1] (overlaps compute below)
        if (ct + 1 < 128) {
            const int kn = (ct + 1) << 6;
            #pragma unroll
            for (int i = 0; i < 8; ++i) {
                int g = wave * 8 + i;
                const u16* gp = ch + (size_t)(kn + (g & 3) * 16 + l15) * D + (g >> 2) * 32 + l4 * 8;
                u16* lb = &As[buf ^ 1][(size_t)g * 512];
                __builtin_amdgcn_global_load_lds(
                    (const __attribute__((address_space(1))) u32*)gp,
                    (__attribute__((address_space(3))) u32*)lb, 16, 0, 0);
            }
        }

        // compute tile ct from As[buf]: per c-iter 1 ds_read_b128 + 4 MFMA
        const u16* cb_t = &As[buf][0];
        f32x4 acc[4];
        #pragma unroll
        for (int nt = 0; nt < 4; ++nt) acc[nt] = (f32x4){0.f, 0.f, 0.f, 0.f};

        #pragma unroll
        for (int c = 0; c < 8; ++c) {
            bf16x8 Af = *(const bf16x8*)(cb_t + (size_t)((c * 4 + wave) * 64 + lane) * 8);
            acc[0] = __builtin_amdgcn_mfma_f32_16x16x32_bf16(Af, Bf[0][c], acc[0], 0, 0, 0);
            acc[1] = __builtin_amdgcn_mfma_f32_16x16x32_bf16(Af, Bf[1][c], acc[1], 0, 0, 0);
            acc[2] = __builtin_amdgcn_mfma_f32_16x16x32_bf16(Af, Bf[2][c], acc[2], 0, 0, 0);
            acc[3] = __builtin_amdgcn_mfma_f32_16x16x32_bf16(Af, Bf[3][c], acc[3], 0, 0, 0);
        }

        // epilogue: t = se - 2*dot ; per-lane top-2 over this wave's 4 codes/row
        f32x4 sev = *(const f32x4*)(se + k0 + wave * 16 + l4 * 4);

        #pragma unroll
        for (int nt = 0; nt < 4; ++nt) {
            float t0 = fmaf(-2.f, acc[nt][0], sev[0]);
            float t1 = fmaf(-2.f, acc[nt][1], sev[1]);
            float t2 = fmaf(-2.f, acc[nt][2], sev[2]);
            float t3 = fmaf(-2.f, acc[nt][3], sev[3]);
            float tmn = fminf(fminf(t0, t1), fminf(t2, t3));
            if (tmn < b1[nt]) {
                #pragma unroll
                for (int r = 0; r < 4; ++r) {
                    float t = fmaf(-2.f, acc[nt][r], sev[r]);
                    int  cv = k0 + wave * 16 + l4 * 4 + r;
                    bool in0 = t < b0[nt];
                    bool in1 = t < b1[nt];
                    float ob0 = b0[nt]; int oc0 = c0[nt];
                    b1[nt] = in0 ? ob0 : (in1 ? t  : b1[nt]);
                    c1[nt] = in0 ? oc0 : (in1 ? cv : c1[nt]);
                    b0[nt] = in0 ? t  : ob0;
                    c0[nt] = in0 ? cv : oc0;
                }
            }
        }

        __syncthreads();   // drain prefetch (vmcnt) + all waves done with As[buf]
        buf ^= 1;
    }

    // ---- cross-wave merge: 16 (wave,l4) groups/row -> 8 slots, top-2-of-union
    // LDS reuse of As (computes all done). Row stride 33 floats (bank spread).
    float* Mv = (float*)&As[0][0];                 // [64][33] values
    u32*   Mc = (u32*)(Mv + 64 * 33);              // [64][33] codes
    #pragma unroll
    for (int nt = 0; nt < 4; ++nt) {
        int rl = nt * 16 + l15;
        int g  = wave * 4 + l4;                    // 0..15
        Mv[rl * 33 + g * 2]     = b0[nt];
        Mv[rl * 33 + g * 2 + 1] = b1[nt];
        Mc[rl * 33 + g * 2]     = (u32)c0[nt];
        Mc[rl * 33 + g * 2 + 1] = (u32)c1[nt];
    }
    __syncthreads();

    for (int tsk = tid; tsk < 512; tsk += 256) {
        int row = tsk >> 3, m = tsk & 7;           // merge groups 2m, 2m+1
        const float* v  = Mv + row * 33 + m * 4;
        const u32*   cc = Mc + row * 33 + m * 4;
        float v00 = v[0],  v01 = v[1],  v10 = v[2],  v11 = v[3];
        u32   c00 = cc[0], c01 = cc[1], c10 = cc[2], c11 = cc[3];
        // best-2 of the (sorted-pair, sorted-pair) union
        bool  aw  = v00 <= v10;
        u32   w0c = aw ? c00 : c10;
        float s1  = aw ? v10 : v00; u32 s1c = aw ? c10 : c00;  // loser of firsts
        float s2  = aw ? v01 : v11; u32 s2c = aw ? c01 : c11;  // winner's second
        u32   w1c = (s2 <= s1) ? s2c : s1c;
        cand[(size_t)(row0 + row) * 16 + m * 2]     = w0c;
        cand[(size_t)(row0 + row) * 16 + m * 2 + 1] = w1c;
    }
}

// ---------------------------------------------------------------------------
// Rescore + output: one wave per row. Coalesced float4 dots over the 16
// candidates (butterfly reduce), fp32 argmin (round-1 formula), write
// quantized + idx + block-reduced loss partial (one atomic per block).
__global__ __launch_bounds__(1024) void vq_rescore_kernel(
    const float* __restrict__ x, const float* __restrict__ cb,
    const float* __restrict__ se, const u32* __restrict__ cand,
    float* __restrict__ out, float* __restrict__ loss_sum)
{
    const int wave = threadIdx.x >> 6;
    const int lane = threadIdx.x & 63;
    const int row  = blockIdx.x * 16 + wave;

    float4 xv = *(const float4*)(x + (size_t)row * D + lane * 4);
    float sx = xv.x * xv.x + xv.y * xv.y + xv.z * xv.z + xv.w * xv.w;
    #pragma unroll
    for (int o = 1; o < 64; o <<= 1) sx += __shfl_xor(sx, o, 64);

    u32 myc = cand[(size_t)row * 16 + (lane & 15)];
    float best = 1e30f; int bk = 0x7fffffff;
    #pragma unroll 4
    for (int j = 0; j < 16; ++j) {
        int code = __shfl((int)myc, j, 64);
        float4 ev = *(const float4*)(cb + (size_t)code * D + lane * 4);
        float p = xv.x * ev.x + xv.y * ev.y + xv.z * ev.z + xv.w * ev.w;
        #pragma unroll
        for (int o = 1; o < 64; o <<= 1) p += __shfl_xor(p, o, 64);
        float dist = (sx + se[code]) - 2.0f * p;
        if (dist < best || (dist == best && code < bk)) { best = dist; bk = code; }
    }

    float4 q = *(const float4*)(cb + (size_t)bk * D + lane * 4);
    *(float4*)(out + (size_t)row * D + lane * 4) = q;
    float dx = q.x - xv.x, dy = q.y - xv.y, dz = q.z - xv.z, dw = q.w - xv.w;
    float s = dx * dx + dy * dy + dz * dz + dw * dw;
    #pragma unroll
    for (int o = 1; o < 64; o <<= 1) s += __shfl_xor(s, o, 64);
    if (lane == 0) out[QELEMS + row] = (float)bk;

    __shared__ float red[16];
    if (lane == 0) red[wave] = s;
    __syncthreads();
    if (threadIdx.x == 0) {
        float t = 0.f;
        #pragma unroll
        for (int w2 = 0; w2 < 16; ++w2) t += red[w2];
        atomicAdd(loss_sum, t);
    }
}

// ---------------------------------------------------------------------------
__global__ void vq_fin_kernel(const float* __restrict__ loss_sum, float* __restrict__ out) {
    out[QELEMS + NROWS] = 1.25f * (*loss_sum) * (1.0f / (float)QELEMS);
}

// ---------------------------------------------------------------------------
extern "C" void kernel_launch(void* const* d_in, const int* in_sizes, int n_in,
                              void* d_out, int out_size, void* d_ws, size_t ws_size,
                              hipStream_t stream) {
    const float* x  = (const float*)d_in[0];   // [16,2048,256] fp32
    const float* cb = (const float*)d_in[1];   // [8192,256] fp32
    float* out = (float*)d_out;

    // bf16 codebook scratch in d_out bytes [0, 4 MiB) — dead before the
    // rescore kernel (which overwrites it with quantized rows).
    u16* ch = (u16*)d_out;

    char* ws = (char*)d_ws;
    float* loss_sum = (float*)ws;               // @0, 4 B
    float* sebuf    = (float*)(ws + 4096);      // 32 KB
    u32*   cand     = (u32*)(ws + 65536);       // 32768*16*4 = 2 MiB

    vq_prep_kernel<<<K / 4, 256, 0, stream>>>(cb, ch, sebuf, loss_sum);
    vq_filter_kernel<<<NROWS / 64, 256, 0, stream>>>(ch, x, sebuf, cand);
    vq_rescore_kernel<<<NROWS / 16, 1024, 0, stream>>>(x, cb, sebuf, cand, out, loss_sum);
    vq_fin_kernel<<<1, 1, 0, stream>>>(loss_sum, out);
}

// Round 2
// 405.094 us; speedup vs baseline: 1.0000x; 1.0000x over previous
//
#include <hip/hip_runtime.h>
#include <hip/hip_bf16.h>
#include <stdint.h>

#define D      256
#define K      8192
#define NROWS  32768          // 16 * 2048
#define QELEMS 8388608        // NROWS * D
// d_out layout (flat f32): [0,QELEMS) quantized, [QELEMS,QELEMS+NROWS) idx, [QELEMS+NROWS] loss

typedef __attribute__((ext_vector_type(8))) short bf16x8;
typedef __attribute__((ext_vector_type(4))) float f32x4;
typedef unsigned int u32;
typedef unsigned short u16;

__device__ __forceinline__ u16 f2bf(float f) {
    u32 b = __float_as_uint(f);
    return (u16)((b + 0x7fffu + ((b >> 16) & 1u)) >> 16);   // RNE
}

// ---------------------------------------------------------------------------
// Prep: cb fp32 -> ch bf16, se[k] = ||cb[k]||^2, zero loss accumulator.
__global__ __launch_bounds__(256) void vq_prep_kernel(
    const float* __restrict__ cb, u16* __restrict__ ch,
    float* __restrict__ se, float* __restrict__ loss_sum) {
    int row = blockIdx.x * 4 + (threadIdx.x >> 6);
    int l = threadIdx.x & 63;
    float4 v = *(const float4*)(cb + (size_t)row * D + l * 4);
    ushort4 o;
    o.x = f2bf(v.x); o.y = f2bf(v.y); o.z = f2bf(v.z); o.w = f2bf(v.w);
    *(ushort4*)(ch + (size_t)row * D + l * 4) = o;
    float s = v.x * v.x + v.y * v.y + v.z * v.z + v.w * v.w;
    #pragma unroll
    for (int off = 32; off > 0; off >>= 1) s += __shfl_down(s, off, 64);
    if (l == 0) se[row] = s;
    if (blockIdx.x == 0 && threadIdx.x == 0) *loss_sum = 0.f;
}

// ---------------------------------------------------------------------------
// Filter v3: NO LDS staging, NO barriers in the scan loop. The bf16 codebook
// (4 MiB) is L2-resident; each wave loads its A-fragments straight from L2
// into VGPRs (global_load_dwordx4; lanes {r,r+16,r+32,r+48} cover one full
// 64B line -> perfectly line-coalesced) and feeds MFMA from registers.
// 2-tile register ping-pong (AfA/AfB) hides L2 latency under the previous
// tile's 32 MFMAs. Waves free-run (no lockstep, no vmcnt(0) drains).
// Partition: wave w owns code-slice w*16 of each 64-code tile, ALL 64 block
// rows in registers (Bf[4][8] = 128 VGPR). Per c-iter: 1 VGPR load + 4 MFMA.
// Per-row candidates: 16 (wave,l4) groups x top-2 -> LDS merge (one barrier,
// after the scan) -> 8 slots x best-2-of-union = 16. Rescore unchanged.
__global__ __launch_bounds__(256, 2) void vq_filter_kernel(
    const u16* __restrict__ ch, const float* __restrict__ x,
    const float* __restrict__ se, u32* __restrict__ cand)
{
    __shared__ float Mv[64 * 33];      // merge values, stride 33 (bank spread)
    __shared__ u32   Mc[64 * 33];      // merge codes

    const int tid  = threadIdx.x;
    const int lane = tid & 63;
    const int wave = tid >> 6;         // 0..3 : which 16-code slice of the tile
    const int l15  = lane & 15;
    const int l4   = lane >> 4;        // 0..3
    const int row0 = blockIdx.x * 64;

    // ---- B operand: ALL 64 block rows x 256 d in registers, f2bf in-register
    bf16x8 Bf[4][8];                   // 128 VGPRs
    #pragma unroll
    for (int nt = 0; nt < 4; ++nt) {
        const float* xr = x + (size_t)(row0 + nt * 16 + l15) * D + l4 * 8;
        #pragma unroll
        for (int c = 0; c < 8; ++c) {
            float4 a = *(const float4*)(xr + c * 32);
            float4 b = *(const float4*)(xr + c * 32 + 4);
            bf16x8 f;
            f[0] = (short)f2bf(a.x); f[1] = (short)f2bf(a.y);
            f[2] = (short)f2bf(a.z); f[3] = (short)f2bf(a.w);
            f[4] = (short)f2bf(b.x); f[5] = (short)f2bf(b.y);
            f[6] = (short)f2bf(b.z); f[7] = (short)f2bf(b.w);
            Bf[nt][c] = f;
        }
    }

    // per-lane top-2 (value, code) per nt-row
    float b0[4], b1[4]; int c0[4], c1[4];
    #pragma unroll
    for (int nt = 0; nt < 4; ++nt) { b0[nt] = 1e30f; b1[nt] = 1e30f; c0[nt] = 0; c1[nt] = 0; }

    // per-lane A pointer: row = wave*16 + l15, d-chunk base = l4*8 elems.
    // Per tile ct the row block advances by 64 codes = 16384 elems; per c-iter
    // +32 elems = 64 B (folds into the 13-bit signed imm offset).
    const u16* apl = ch + (size_t)(wave * 16 + l15) * D + l4 * 8;

#define LOAD_AF(AF, CT) do {                                                  \
    const u16* _p = apl + (size_t)(CT) * 16384;                               \
    _Pragma("unroll")                                                         \
    for (int c = 0; c < 8; ++c) (AF)[c] = *(const bf16x8*)(_p + c * 32);      \
} while (0)

#define COMP_TILE(AF, CT) do {                                                \
    const int k0 = (CT) << 6;                                                 \
    f32x4 sev = *(const f32x4*)(se + k0 + wave * 16 + l4 * 4);                \
    f32x4 acc[4];                                                             \
    _Pragma("unroll")                                                         \
    for (int nt = 0; nt < 4; ++nt) acc[nt] = (f32x4){0.f, 0.f, 0.f, 0.f};     \
    _Pragma("unroll")                                                         \
    for (int c = 0; c < 8; ++c) {                                             \
        acc[0] = __builtin_amdgcn_mfma_f32_16x16x32_bf16((AF)[c], Bf[0][c], acc[0], 0, 0, 0); \
        acc[1] = __builtin_amdgcn_mfma_f32_16x16x32_bf16((AF)[c], Bf[1][c], acc[1], 0, 0, 0); \
        acc[2] = __builtin_amdgcn_mfma_f32_16x16x32_bf16((AF)[c], Bf[2][c], acc[2], 0, 0, 0); \
        acc[3] = __builtin_amdgcn_mfma_f32_16x16x32_bf16((AF)[c], Bf[3][c], acc[3], 0, 0, 0); \
    }                                                                         \
    _Pragma("unroll")                                                         \
    for (int nt = 0; nt < 4; ++nt) {                                          \
        float t0 = fmaf(-2.f, acc[nt][0], sev[0]);                            \
        float t1 = fmaf(-2.f, acc[nt][1], sev[1]);                            \
        float t2 = fmaf(-2.f, acc[nt][2], sev[2]);                            \
        float t3 = fmaf(-2.f, acc[nt][3], sev[3]);                            \
        float tmn = fminf(fminf(t0, t1), fminf(t2, t3));                      \
        if (tmn < b1[nt]) {                                                   \
            _Pragma("unroll")                                                 \
            for (int r = 0; r < 4; ++r) {                                     \
                float t = fmaf(-2.f, acc[nt][r], sev[r]);                     \
                int  cv = k0 + wave * 16 + l4 * 4 + r;                        \
                bool in0 = t < b0[nt];                                        \
                bool in1 = t < b1[nt];                                        \
                float ob0 = b0[nt]; int oc0 = c0[nt];                         \
                b1[nt] = in0 ? ob0 : (in1 ? t  : b1[nt]);                     \
                c1[nt] = in0 ? oc0 : (in1 ? cv : c1[nt]);                     \
                b0[nt] = in0 ? t  : ob0;                                      \
                c0[nt] = in0 ? cv : oc0;                                      \
            }                                                                 \
        }                                                                     \
    }                                                                         \
} while (0)

    // ---- free-running scan: 128 tiles of 64 codes, 2-tile reg ping-pong ----
    bf16x8 AfA[8], AfB[8];             // 2 x 32 VGPR
    LOAD_AF(AfA, 0);
    #pragma unroll 1
    for (int ct = 0; ct < 128; ct += 2) {
        LOAD_AF(AfB, ct + 1);          // issue t+1 loads before t's MFMAs
        COMP_TILE(AfA, ct);
        if (ct + 2 < 128) LOAD_AF(AfA, ct + 2);
        COMP_TILE(AfB, ct + 1);
    }
#undef LOAD_AF
#undef COMP_TILE

    // ---- cross-wave merge: 16 (wave,l4) groups/row -> 8 slots, top-2-of-union
    #pragma unroll
    for (int nt = 0; nt < 4; ++nt) {
        int rl = nt * 16 + l15;
        int g  = wave * 4 + l4;                    // 0..15
        Mv[rl * 33 + g * 2]     = b0[nt];
        Mv[rl * 33 + g * 2 + 1] = b1[nt];
        Mc[rl * 33 + g * 2]     = (u32)c0[nt];
        Mc[rl * 33 + g * 2 + 1] = (u32)c1[nt];
    }
    __syncthreads();

    for (int tsk = tid; tsk < 512; tsk += 256) {
        int row = tsk >> 3, m = tsk & 7;           // merge groups 2m, 2m+1
        const float* v  = Mv + row * 33 + m * 4;
        const u32*   cc = Mc + row * 33 + m * 4;
        float v00 = v[0],  v01 = v[1],  v10 = v[2],  v11 = v[3];
        u32   c00 = cc[0], c01 = cc[1], c10 = cc[2], c11 = cc[3];
        // best-2 of the (sorted-pair, sorted-pair) union
        bool  aw  = v00 <= v10;
        u32   w0c = aw ? c00 : c10;
        float s1  = aw ? v10 : v00; u32 s1c = aw ? c10 : c00;  // loser of firsts
        float s2  = aw ? v01 : v11; u32 s2c = aw ? c01 : c11;  // winner's second
        u32   w1c = (s2 <= s1) ? s2c : s1c;
        cand[(size_t)(row0 + row) * 16 + m * 2]     = w0c;
        cand[(size_t)(row0 + row) * 16 + m * 2 + 1] = w1c;
    }
}

// ---------------------------------------------------------------------------
// Rescore + output: one wave per row. Coalesced float4 dots over the 16
// candidates (butterfly reduce), fp32 argmin (round-1 formula), write
// quantized + idx + block-reduced loss partial (one atomic per block).
__global__ __launch_bounds__(1024) void vq_rescore_kernel(
    const float* __restrict__ x, const float* __restrict__ cb,
    const float* __restrict__ se, const u32* __restrict__ cand,
    float* __restrict__ out, float* __restrict__ loss_sum)
{
    const int wave = threadIdx.x >> 6;
    const int lane = threadIdx.x & 63;
    const int row  = blockIdx.x * 16 + wave;

    float4 xv = *(const float4*)(x + (size_t)row * D + lane * 4);
    float sx = xv.x * xv.x + xv.y * xv.y + xv.z * xv.z + xv.w * xv.w;
    #pragma unroll
    for (int o = 1; o < 64; o <<= 1) sx += __shfl_xor(sx, o, 64);

    u32 myc = cand[(size_t)row * 16 + (lane & 15)];
    float best = 1e30f; int bk = 0x7fffffff;
    #pragma unroll 4
    for (int j = 0; j < 16; ++j) {
        int code = __shfl((int)myc, j, 64);
        float4 ev = *(const float4*)(cb + (size_t)code * D + lane * 4);
        float p = xv.x * ev.x + xv.y * ev.y + xv.z * ev.z + xv.w * ev.w;
        #pragma unroll
        for (int o = 1; o < 64; o <<= 1) p += __shfl_xor(p, o, 64);
        float dist = (sx + se[code]) - 2.0f * p;
        if (dist < best || (dist == best && code < bk)) { best = dist; bk = code; }
    }

    float4 q = *(const float4*)(cb + (size_t)bk * D + lane * 4);
    *(float4*)(out + (size_t)row * D + lane * 4) = q;
    float dx = q.x - xv.x, dy = q.y - xv.y, dz = q.z - xv.z, dw = q.w - xv.w;
    float s = dx * dx + dy * dy + dz * dz + dw * dw;
    #pragma unroll
    for (int o = 1; o < 64; o <<= 1) s += __shfl_xor(s, o, 64);
    if (lane == 0) out[QELEMS + row] = (float)bk;

    __shared__ float red[16];
    if (lane == 0) red[wave] = s;
    __syncthreads();
    if (threadIdx.x == 0) {
        float t = 0.f;
        #pragma unroll
        for (int w2 = 0; w2 < 16; ++w2) t += red[w2];
        atomicAdd(loss_sum, t);
    }
}

// ---------------------------------------------------------------------------
__global__ void vq_fin_kernel(const float* __restrict__ loss_sum, float* __restrict__ out) {
    out[QELEMS + NROWS] = 1.25f * (*loss_sum) * (1.0f / (float)QELEMS);
}

// ---------------------------------------------------------------------------
extern "C" void kernel_launch(void* const* d_in, const int* in_sizes, int n_in,
                              void* d_out, int out_size, void* d_ws, size_t ws_size,
                              hipStream_t stream) {
    const float* x  = (const float*)d_in[0];   // [16,2048,256] fp32
    const float* cb = (const float*)d_in[1];   // [8192,256] fp32
    float* out = (float*)d_out;

    // bf16 codebook scratch in d_out bytes [0, 4 MiB) — dead before the
    // rescore kernel (which overwrites it with quantized rows).
    u16* ch = (u16*)d_out;

    char* ws = (char*)d_ws;
    float* loss_sum = (float*)ws;               // @0, 4 B
    float* sebuf    = (float*)(ws + 4096);      // 32 KB
    u32*   cand     = (u32*)(ws + 65536);       // 32768*16*4 = 2 MiB

    vq_prep_kernel<<<K / 4, 256, 0, stream>>>(cb, ch, sebuf, loss_sum);
    vq_filter_kernel<<<NROWS / 64, 256, 0, stream>>>(ch, x, sebuf, cand);
    vq_rescore_kernel<<<NROWS / 16, 1024, 0, stream>>>(x, cb, sebuf, cand, out, loss_sum);
    vq_fin_kernel<<<1, 1, 0, stream>>>(loss_sum, out);
}